// Round 9
// baseline (427.320 us; speedup 1.0000x reference)
//
#include <hip/hip_runtime.h>

typedef _Float16 half8 __attribute__((ext_vector_type(8)));
typedef float floatx4 __attribute__((ext_vector_type(4)));

#define AS1 __attribute__((address_space(1)))
#define AS3 __attribute__((address_space(3)))

// ---------------------------------------------------------------------------
// W transpose + fp32->fp16: W [1024][1024] (k,n) -> Wt [1024][1024] (n,k)
// ---------------------------------------------------------------------------
__global__ __launch_bounds__(256) void wtrans_kernel(
    const float* __restrict__ W0, const float* __restrict__ W1,
    const float* __restrict__ W2, _Float16* __restrict__ Wt)
{
    __shared__ _Float16 t[64 * 72];
    const float* W = (blockIdx.z == 0) ? W0 : (blockIdx.z == 1) ? W1 : W2;
    _Float16* O = Wt + (long)blockIdx.z * 1048576;
    const int tid = threadIdx.x;
    const int kb = blockIdx.y * 64, nb = blockIdx.x * 64;
#pragma unroll
    for (int i = 0; i < 4; i++) {
        int r = (tid >> 4) + i * 16;
        int c = (tid & 15) * 4;
        floatx4 w = *(const floatx4*)&W[(long)(kb + r) * 1024 + nb + c];
#pragma unroll
        for (int j = 0; j < 4; j++) t[(c + j) * 72 + r] = (_Float16)w[j];
    }
    __syncthreads();
    const int c = tid >> 2, rch = (tid & 3) * 16;
    half8 v0 = *(const half8*)&t[c * 72 + rch];
    half8 v1 = *(const half8*)&t[c * 72 + rch + 8];
    _Float16* o = &O[(long)(nb + c) * 1024 + kb + rch];
    *(half8*)o = v0;
    *(half8*)(o + 8) = v1;
}

// ---------------------------------------------------------------------------
// fp32 -> fp16 cast, 8 elems/thread, grid-stride
// ---------------------------------------------------------------------------
__global__ __launch_bounds__(256) void f32_to_f16_kernel(
    const float* __restrict__ in, _Float16* __restrict__ out, int n)
{
    for (long i = ((long)blockIdx.x * 256 + threadIdx.x) * 8; i < n;
         i += (long)gridDim.x * 256 * 8) {
        floatx4 a = *(const floatx4*)&in[i];
        floatx4 b = *(const floatx4*)&in[i + 4];
        half8 h;
#pragma unroll
        for (int e = 0; e < 4; e++) { h[e] = (_Float16)a[e]; h[e + 4] = (_Float16)b[e]; }
        *(half8*)&out[i] = h;
    }
}

// ---------------------------------------------------------------------------
// Old m97-style 128x128 GEMM — kept ONLY for MODE 1 (V-proj, transposed out).
// ---------------------------------------------------------------------------
template <int MODE>
__global__ __launch_bounds__(256) void gemm128_kernel(
    const _Float16* __restrict__ A, const _Float16* __restrict__ Bt,
    void* __restrict__ Cv, const float* __restrict__ bias,
    const float* __restrict__ bias2,
    int nx, int ny,
    int K, int lda, int ldb, int ldc,
    long aBatch, long bBatch, long cBatch, float scale)
{
    constexpr int SMEM_ELEMS = (MODE == 1) ? 17408 : 16384;
    __shared__ _Float16 smem[SMEM_ELEMS];
    _Float16* Ash = smem;
    _Float16* Bsh = smem + 8192;

    const int tid = threadIdx.x;
    const int wave = tid >> 6, lane = tid & 63;
    const int quad = lane >> 4, lr = lane & 15;
    const int wm = wave & 1, wn = wave >> 1;

    const int P = gridDim.x >> 3;
    const int g = (blockIdx.x & 7) * P + (blockIdx.x >> 3);
    const int pplane = nx * ny;
    const int z = g / pplane;
    const int rr = g - z * pplane;
    const int by = rr / nx;
    const int bx = rr - by * nx;
    const int m0 = by * 128, n0 = bx * 128;

    const _Float16* Ab = A + (long)z * aBatch;
    const _Float16* Bb = Bt + (long)z * bBatch;

    const int srow = tid >> 2;
    const int scol = (tid & 3) * 8;
    const long ag0 = (long)(m0 + srow) * lda + scol;
    const long bg0 = (long)(n0 + srow) * ldb + scol;
    const int sdst = tid * 8;

    floatx4 acc[4][4] = {};

    for (int k0 = 0; k0 < K; k0 += 64) {
#pragma unroll
        for (int s = 0; s < 2; s++) {
            const int kk = k0 + s * 32;
            const int so = s * 4096;
            __builtin_amdgcn_global_load_lds(
                (AS1 void*)(Ab + ag0 + kk), (AS3 void*)(Ash + so + sdst), 16, 0, 0);
            __builtin_amdgcn_global_load_lds(
                (AS1 void*)(Ab + ag0 + (long)64 * lda + kk), (AS3 void*)(Ash + so + sdst + 2048), 16, 0, 0);
            __builtin_amdgcn_global_load_lds(
                (AS1 void*)(Bb + bg0 + kk), (AS3 void*)(Bsh + so + sdst), 16, 0, 0);
            __builtin_amdgcn_global_load_lds(
                (AS1 void*)(Bb + bg0 + (long)64 * ldb + kk), (AS3 void*)(Bsh + so + sdst + 2048), 16, 0, 0);
        }
        __syncthreads();

#pragma unroll
        for (int s = 0; s < 2; s++) {
            const int so = s * 4096;
            half8 aF[4], bF[4];
#pragma unroll
            for (int i = 0; i < 4; i++) {
                aF[i] = *(const half8*)&Ash[so + (wm * 64 + i * 16 + lr) * 32 + quad * 8];
                bF[i] = *(const half8*)&Bsh[so + (wn * 64 + i * 16 + lr) * 32 + quad * 8];
            }
#pragma unroll
            for (int mi = 0; mi < 4; mi++)
#pragma unroll
                for (int ni = 0; ni < 4; ni++)
                    acc[mi][ni] = __builtin_amdgcn_mfma_f32_16x16x32_f16(
                        aF[mi], bF[ni], acc[mi][ni], 0, 0, 0);
        }
        __syncthreads();
    }

    if constexpr (MODE == 0) {
        _Float16* C = (_Float16*)Cv + (long)z * cBatch;
        const float* bz = (z == 0 || !bias2) ? bias : bias2;
#pragma unroll
        for (int ni = 0; ni < 4; ni++) {
            const int n = n0 + wn * 64 + ni * 16 + lr;
            const float bv_ = bz ? bz[n] : 0.0f;
#pragma unroll
            for (int mi = 0; mi < 4; mi++) {
                const int mb = m0 + wm * 64 + mi * 16 + quad * 4;
#pragma unroll
                for (int r = 0; r < 4; r++)
                    C[(long)(mb + r) * ldc + n] = (_Float16)((acc[mi][ni][r] + bv_) * scale);
            }
        }
    } else if constexpr (MODE == 1) {
        _Float16* ctile = smem;
#pragma unroll
        for (int ni = 0; ni < 4; ni++) {
            const int nl = wn * 64 + ni * 16 + lr;
            const float bv_ = bias ? bias[n0 + nl] : 0.0f;
#pragma unroll
            for (int mi = 0; mi < 4; mi++) {
                const int ml = wm * 64 + mi * 16 + quad * 4;
#pragma unroll
                for (int r = 0; r < 4; r++)
                    ctile[nl * 136 + ml + r] = (_Float16)((acc[mi][ni][r] + bv_) * scale);
            }
        }
        __syncthreads();
        _Float16* C = (_Float16*)Cv + (long)(m0 >> 11) * cBatch;
        const int t0 = m0 & 2047;
#pragma unroll
        for (int p = 0; p < 8; p++) {
            const int row = p * 16 + (tid >> 4);
            const int seg = (tid & 15) * 8;
            half8 v = *(const half8*)&ctile[row * 136 + seg];
            *(half8*)&C[(long)(n0 + row) * ldc + t0 + seg] = v;
        }
    } else {
        float* C = (float*)Cv + (long)z * cBatch;
#pragma unroll
        for (int ni = 0; ni < 4; ni++) {
            const int n = n0 + wn * 64 + ni * 16 + lr;
#pragma unroll
            for (int mi = 0; mi < 4; mi++) {
                const int mb = m0 + wm * 64 + mi * 16 + quad * 4;
#pragma unroll
                for (int r = 0; r < 4; r++)
                    C[(long)(mb + r) * ldc + n] = acc[mi][ni][r] * scale;
            }
        }
    }
}

// ---------------------------------------------------------------------------
// 256x256 GEMM, one-barrier-per-phase + BALANCED READS (round 9).
//   C[m][n] = sum_k A[m][k] * Bt[n][k]   (fp16 row-major)
// 512 thr = 8 waves (2Mx4N), per-wave 128x64, BK=64, LDS 128K XOR-swizzled.
//
// Round-8 result: one barrier/phase -> 33.8% MfmaUtil. Remaining fat: reads
// per phase were 12/4/8/0 (p0 = A-half + B-half, p3 = none) -> p0's LDS
// burst serializes before its MFMA while p3 idles the LDS pipe. m201 (62%)
// keeps 4-8 reads/phase. THIS ROUND: balance to 8/4/8/4 by reading each
// B-half 2-4 phases AHEAD of use into 4 static register sets B00/B01/B10/
// B11 (static indexing only — rule 20), using p3/p7's empty read slots.
//
// Phase map (iter = tiles 2i [buf0] / 2i+1 [buf1]; t1=2i+1,t2=2i+2,t3=2i+3):
//  p0: rd A(b0,h0)[8]     st b1.B1(t1)  MFMA(0,0)xB00   <- B00 read prev p7
//  p1: rd B01=B(b0,h1)[4] st b1.A1(t1)  MFMA(0,1)xB01
//  p2: rd A(b0,h1)[8]     st b0.B0(t2)  MFMA(1,1)xB01
//  p3: rd B10=B(b1,h0)[4] st b0.A0(t2)  MFMA(1,0)xB00
//  p4: rd A(b1,h0)[8]     st b0.B1(t2)  MFMA(0,0)xB10
//  p5: rd B11=B(b1,h1)[4] st b0.A1(t2)  MFMA(0,1)xB11
//  p6: rd A(b1,h1)[8]     st b1.B0(t3)  MFMA(1,1)xB11
//  p7: rd B00=B(b0,h0)[4] st b1.A0(t3)  MFMA(1,0)xB10   <- B00 now t2's data
// vmcnt(8) (= newest 4 half-stages in flight) before EVERY barrier; every
// read's staging is >=5 slots old at its covering wait (verified per-read);
// every region's read->restage gap = 3 phases (WAR safe). Main loop is
// UNCONDITIONAL (i < NI-1); peeled last iter stages only b1.B1/A1 and
// drains 8,8,6,4,2,0 (window shifts because peel p2+ stage nothing).
// MODE 0: fp16 out (+bias per z)*scale.  MODE 2: fp32 out.
// ---------------------------------------------------------------------------
#define STAGE_A(d, h, kt) do { \
    __builtin_amdgcn_global_load_lds((AS1 void*)(Ap + (long)((h) * 64) * lda + (long)(kt) * 64), \
        (AS3 void*)(Ash + (d) * 16384 + (h) * 8192 + sdst), 16, 0, 0); \
    __builtin_amdgcn_global_load_lds((AS1 void*)(Ap + (long)((h) * 64 + 128) * lda + (long)(kt) * 64), \
        (AS3 void*)(Ash + (d) * 16384 + (h) * 8192 + 4096 + sdst), 16, 0, 0); \
} while (0)

#define STAGE_B(d, h, kt) do { \
    __builtin_amdgcn_global_load_lds((AS1 void*)(Bp0 + (long)((h) * 32) * ldb + (long)(kt) * 64), \
        (AS3 void*)(Bsh + (d) * 16384 + (h) * 8192 + sdst), 16, 0, 0); \
    __builtin_amdgcn_global_load_lds((AS1 void*)(Bp1 + (long)((h) * 32) * ldb + (long)(kt) * 64), \
        (AS3 void*)(Bsh + (d) * 16384 + (h) * 8192 + 4096 + sdst), 16, 0, 0); \
} while (0)

#define LDA_FRAGS(d, mh) do { \
    _Pragma("unroll") for (int mi_ = 0; mi_ < 4; mi_++) { \
        const _Float16* p_ = &Ash[(d) * 16384 + (mh) * 8192 + (arow + mi_ * 16) * 64]; \
        aF[mi_][0] = *(const half8*)&p_[kq0]; \
        aF[mi_][1] = *(const half8*)&p_[kq1]; \
    } \
} while (0)

// read B-half (d,nh) into the named 2x2 register set
#define LDB_SET(DSTB, d, nh) do { \
    _Pragma("unroll") for (int ni_ = 0; ni_ < 2; ni_++) { \
        const _Float16* p_ = &Bsh[(d) * 16384 + (nh) * 8192 + (brow + ni_ * 16) * 64]; \
        DSTB[ni_][0] = *(const half8*)&p_[kq0]; \
        DSTB[ni_][1] = *(const half8*)&p_[kq1]; \
    } \
} while (0)

#define MFMA16(mh, nh, BSET) do { \
    __builtin_amdgcn_s_setprio(1); \
    _Pragma("unroll") for (int mi_ = 0; mi_ < 4; mi_++) \
    _Pragma("unroll") for (int ni_ = 0; ni_ < 2; ni_++) { \
        acc[(mh) * 4 + mi_][(nh) * 2 + ni_] = __builtin_amdgcn_mfma_f32_16x16x32_f16( \
            aF[mi_][0], BSET[ni_][0], acc[(mh) * 4 + mi_][(nh) * 2 + ni_], 0, 0, 0); \
        acc[(mh) * 4 + mi_][(nh) * 2 + ni_] = __builtin_amdgcn_mfma_f32_16x16x32_f16( \
            aF[mi_][1], BSET[ni_][1], acc[(mh) * 4 + mi_][(nh) * 2 + ni_], 0, 0, 0); \
    } \
    __builtin_amdgcn_s_setprio(0); \
} while (0)

// counted wait + barrier + compiler-only memory fences (one barrier/phase)
#define VMBAR(n) do { \
    asm volatile("s_waitcnt vmcnt(" #n ")" ::: "memory"); \
    __builtin_amdgcn_s_barrier(); \
    asm volatile("" ::: "memory"); \
} while (0)

template <int MODE>
__global__ __launch_bounds__(512, 2) void gemm256_kernel(
    const _Float16* __restrict__ A, const _Float16* __restrict__ Bt,
    void* __restrict__ Cv, const float* __restrict__ bias,
    const float* __restrict__ bias2,
    int nx, int ny, int K, int lda, int ldb, int ldc,
    long aBatch, long bBatch, long cBatch, float scale)
{
    __shared__ _Float16 smem[65536];   // 128 KiB
    _Float16* Ash = smem;
    _Float16* Bsh = smem + 32768;

    const int tid = threadIdx.x;
    const int wave = tid >> 6, lane = tid & 63;
    const int quad = lane >> 4, lr = lane & 15;
    const int wm = wave >> 2, wn = wave & 3;

    // XCD-aware swizzle (grid % 8 == 0 for all our launches)
    const int P = gridDim.x >> 3;
    const int g = (blockIdx.x & 7) * P + (blockIdx.x >> 3);
    const int pplane = nx * ny;
    const int z = g / pplane;
    const int rr = g - z * pplane;
    const int by = rr / nx;
    const int bx = rr - by * nx;
    const int m0 = by * 256, n0 = bx * 256;

    const _Float16* Ab = A + (long)z * aBatch;
    const _Float16* Bb = Bt + (long)z * bBatch;

    // ---- staging geometry: thread -> (local row sr, swizzled 16B chunk) ----
    const int sr0 = tid >> 3;                   // 0..63 (load 0); load 1 adds 64
    const int sc0 = (tid & 7) ^ (sr0 & 7);      // pre-swizzled global chunk
    const _Float16* Ap = Ab + (long)(m0 + sr0) * lda + sc0 * 8;
    const int bc0 = (sr0 & 31) + ((sr0 >> 5) << 6);          // B col, load 0, h=0
    const int bc1 = (sr0 & 31) + (((sr0 >> 5) + 2) << 6);    // B col, load 1, h=0
    const _Float16* Bp0 = Bb + (long)(n0 + bc0) * ldb + sc0 * 8;
    const _Float16* Bp1 = Bb + (long)(n0 + bc1) * ldb + sc0 * 8;
    const int sdst = tid * 8;                   // LDS elem offset (linear dest)

    // ---- fragment-read geometry (k-chunk XOR'd back) ----
    const int kq0 = (quad * 8) ^ ((lr & 7) << 3);
    const int kq1 = (32 + quad * 8) ^ ((lr & 7) << 3);
    const int arow = wm * 64 + lr;              // + mi*16 = A local row
    const int brow = wn * 32 + lr;              // + ni*16 = B local row

    half8 aF[4][2];                      // current A-half (same-phase read->use)
    half8 B00[2][2], B01[2][2], B10[2][2], B11[2][2];   // 4 static B sets
    floatx4 acc[8][4] = {};
    const int NT = K >> 6;       // even (16 or 32)
    const int NI = NT >> 1;

    // ---- prologue: t0 {B0,A0,B1,A1} + t1 {B0,A0} = 6 half-stages ----
    STAGE_B(0, 0, 0); STAGE_A(0, 0, 0); STAGE_B(0, 1, 0); STAGE_A(0, 1, 0);
    STAGE_B(1, 0, 1); STAGE_A(1, 0, 1);
    asm volatile("s_waitcnt vmcnt(4)" ::: "memory");   // t0's 4 halves landed
    __builtin_amdgcn_s_barrier();
    asm volatile("" ::: "memory");
    LDB_SET(B00, 0, 0);          // bF0 of tile 0 (consumed at p0/p3)

    // ---- main loop: NI-1 full iterations, stages unconditional ----
    for (int i = 0; i < NI - 1; ++i) {
        const int t1 = 2 * i + 1, t2 = 2 * i + 2, t3 = 2 * i + 3;  // all < NT
        // p0
        LDA_FRAGS(0, 0);
        STAGE_B(1, 1, t1);
        VMBAR(8);
        MFMA16(0, 0, B00);
        // p1
        LDB_SET(B01, 0, 1);
        STAGE_A(1, 1, t1);
        VMBAR(8);
        MFMA16(0, 1, B01);
        // p2
        LDA_FRAGS(0, 1);
        STAGE_B(0, 0, t2);
        VMBAR(8);
        MFMA16(1, 1, B01);
        // p3
        LDB_SET(B10, 1, 0);
        STAGE_A(0, 0, t2);
        VMBAR(8);
        MFMA16(1, 0, B00);
        // p4
        LDA_FRAGS(1, 0);
        STAGE_B(0, 1, t2);
        VMBAR(8);
        MFMA16(0, 0, B10);
        // p5
        LDB_SET(B11, 1, 1);
        STAGE_A(0, 1, t2);
        VMBAR(8);
        MFMA16(0, 1, B11);
        // p6
        LDA_FRAGS(1, 1);
        STAGE_B(1, 0, t3);
        VMBAR(8);
        MFMA16(1, 1, B11);
        // p7 (B00 <- b0.B0 now holds t2's data, staged p2, landed by p6's wait)
        LDB_SET(B00, 0, 0);
        STAGE_A(1, 0, t3);
        VMBAR(8);
        MFMA16(1, 0, B10);
    }

    // ---- peeled last iteration: tiles NT-2 (b0), NT-1 (b1) ----
    {
        const int tl = NT - 1;
        // p0
        LDA_FRAGS(0, 0);
        STAGE_B(1, 1, tl);
        VMBAR(8);
        MFMA16(0, 0, B00);
        // p1
        LDB_SET(B01, 0, 1);
        STAGE_A(1, 1, tl);
        VMBAR(8);
        MFMA16(0, 1, B01);
        // p2 (no stage -> window shifts: need lm.p5 landed for these reads,
        //     and lm.p6 landed for p3's B10 read -> vmcnt(6))
        LDA_FRAGS(0, 1);
        VMBAR(6);
        MFMA16(1, 1, B01);
        // p3 (need lm.p7 landed for p4's A reads -> vmcnt(4))
        LDB_SET(B10, 1, 0);
        VMBAR(4);
        MFMA16(1, 0, B00);
        // p4 (need peel.p0 landed for p5's B11 read -> vmcnt(2))
        LDA_FRAGS(1, 0);
        VMBAR(2);
        MFMA16(0, 0, B10);
        // p5 (need peel.p1 landed for p6's A reads -> vmcnt(0))
        LDB_SET(B11, 1, 1);
        VMBAR(0);
        MFMA16(0, 1, B11);
        // p6/p7: all staging landed; no more barriers needed
        LDA_FRAGS(1, 1);
        MFMA16(1, 1, B11);
        MFMA16(1, 0, B10);
    }

    // ---- epilogue ----  C/D frag: m = quad*4 + r, n = lane&15
    if constexpr (MODE == 0) {
        _Float16* C = (_Float16*)Cv + (long)z * cBatch;
        const float* bz = (z == 0 || !bias2) ? bias : bias2;
#pragma unroll
        for (int ni = 0; ni < 4; ni++) {
            const int n = n0 + wn * 64 + ni * 16 + lr;
            const float bv_ = bz ? bz[n] : 0.0f;
#pragma unroll
            for (int mi = 0; mi < 8; mi++) {
                const int mb = m0 + wm * 128 + mi * 16 + quad * 4;
#pragma unroll
                for (int r = 0; r < 4; r++)
                    C[(long)(mb + r) * ldc + n] = (_Float16)((acc[mi][ni][r] + bv_) * scale);
            }
        }
    } else {
        float* C = (float*)Cv + (long)z * cBatch;
#pragma unroll
        for (int ni = 0; ni < 4; ni++) {
            const int n = n0 + wn * 64 + ni * 16 + lr;
#pragma unroll
            for (int mi = 0; mi < 8; mi++) {
                const int mb = m0 + wm * 128 + mi * 16 + quad * 4;
#pragma unroll
                for (int r = 0; r < 4; r++)
                    C[(long)(mb + r) * ldc + n] = acc[mi][ni][r] * scale;
            }
        }
    }
}

#undef STAGE_A
#undef STAGE_B
#undef LDA_FRAGS
#undef LDB_SET
#undef MFMA16
#undef VMBAR

// ---------------------------------------------------------------------------
// row softmax, in place, fp16. One wave per row of 2048. block=256 -> 4 rows.
// ---------------------------------------------------------------------------
__global__ __launch_bounds__(256) void softmax_kernel(_Float16* __restrict__ buf)
{
    const int lane = threadIdx.x & 63;
    const long row = (long)blockIdx.x * 4 + (threadIdx.x >> 6);
    _Float16* p = buf + row * 2048;

    float f[32];
#pragma unroll
    for (int j = 0; j < 4; j++) {
        half8 v = *(const half8*)&p[lane * 8 + j * 512];
#pragma unroll
        for (int e = 0; e < 8; e++) f[j * 8 + e] = (float)v[e];
    }
    float m = -1e30f;
#pragma unroll
    for (int i = 0; i < 32; i++) m = fmaxf(m, f[i]);
#pragma unroll
    for (int off = 32; off; off >>= 1) m = fmaxf(m, __shfl_xor(m, off, 64));
    float s = 0.0f;
#pragma unroll
    for (int i = 0; i < 32; i++) { f[i] = __expf(f[i] - m); s += f[i]; }
#pragma unroll
    for (int off = 32; off; off >>= 1) s += __shfl_xor(s, off, 64);
    const float inv = 1.0f / s;
#pragma unroll
    for (int j = 0; j < 4; j++) {
        half8 v;
#pragma unroll
        for (int e = 0; e < 8; e++) v[e] = (_Float16)(f[j * 8 + e] * inv);
        *(half8*)&p[lane * 8 + j * 512] = v;
    }
}

// ---------------------------------------------------------------------------
// B=8, S=2048, D=1024.  Workspace layout (bytes):
//   Q   fp16 [16384][1024]            @ 0          (33,554,432)
//   Kb  fp16 [16384][1024]            @ 33,554,432 (33,554,432)   (contig w/ Q)
//   Vt  fp16 [8][1024][2048]          @ 67,108,864 (33,554,432)
//   Sc  fp16 [8][2048][2048]          @ 100,663,296 (67,108,864)  (xb aliased)
//   Wt  fp16 [3][1024][1024]          @ 167,772,160 (6,291,456)
// total 174,063,616
// ---------------------------------------------------------------------------
extern "C" void kernel_launch(void* const* d_in, const int* in_sizes, int n_in,
                              void* d_out, int out_size, void* d_ws, size_t ws_size,
                              hipStream_t stream)
{
    const float* x  = (const float*)d_in[0];
    const float* Wq = (const float*)d_in[1];
    const float* bq = (const float*)d_in[2];
    const float* Wk = (const float*)d_in[3];
    const float* bk = (const float*)d_in[4];
    const float* Wv = (const float*)d_in[5];
    const float* bv = (const float*)d_in[6];

    if (ws_size < 174063616u) return;  // cannot run

    char* ws = (char*)d_ws;
    _Float16* Q  = (_Float16*)(ws + 0);
    _Float16* Vt = (_Float16*)(ws + 67108864);
    _Float16* Sc = (_Float16*)(ws + 100663296);
    _Float16* Wt = (_Float16*)(ws + 167772160);
    _Float16* xb = Sc;  // aliased: xb dead before Sc is written
    _Float16* Kb = Q + 16777216;
    float* out = (float*)d_out;

    wtrans_kernel<<<dim3(16, 16, 3), 256, 0, stream>>>(Wq, Wk, Wv, Wt);
    f32_to_f16_kernel<<<2048, 256, 0, stream>>>(x, xb, 16777216);

    // Q and K projections fused via z: M=16384, N=1024, K=1024 -> 512 blocks
    gemm256_kernel<0><<<512, 512, 0, stream>>>(
        xb, Wt, Q, bq, bk, 4, 64, 1024, 1024, 1024, 1024,
        0, 1048576, 16777216, 1.0f);
    // V projection -> Vt [b][d][t] (old 128^2 MODE-1 kernel), 1024 blocks
    gemm128_kernel<1><<<1024, 256, 0, stream>>>(
        xb, Wt + 2097152, Vt, bv, nullptr, 8, 128, 1024, 1024, 1024, 2048,
        0, 0, 2097152, 1.0f);

    // scores = Q K^T / 32 : per-batch M=N=2048, K=1024 -> 512 blocks
    gemm256_kernel<0><<<512, 512, 0, stream>>>(
        Q, Kb, Sc, nullptr, nullptr, 8, 8, 1024, 1024, 1024, 2048,
        2097152, 2097152, 4194304, 0.03125f);

    softmax_kernel<<<4096, 256, 0, stream>>>(Sc);

    // out = P V : per-batch M=2048, N=1024, K=2048 -> 256 blocks
    gemm256_kernel<2><<<256, 512, 0, stream>>>(
        Sc, Vt, out, nullptr, nullptr, 4, 8, 2048, 2048, 2048, 1024,
        4194304, 2097152, 2097152, 1.0f);
}

// Round 10
// 408.971 us; speedup vs baseline: 1.0449x; 1.0449x over previous
//
#include <hip/hip_runtime.h>

typedef _Float16 half8 __attribute__((ext_vector_type(8)));
typedef _Float16 half4 __attribute__((ext_vector_type(4)));
typedef float floatx4 __attribute__((ext_vector_type(4)));

#define AS1 __attribute__((address_space(1)))
#define AS3 __attribute__((address_space(3)))

// ---------------------------------------------------------------------------
// W transpose + fp32->fp16: W [1024][1024] (k,n) -> Wt [1024][1024] (n,k)
// ---------------------------------------------------------------------------
__global__ __launch_bounds__(256) void wtrans_kernel(
    const float* __restrict__ W0, const float* __restrict__ W1,
    const float* __restrict__ W2, _Float16* __restrict__ Wt)
{
    __shared__ _Float16 t[64 * 72];
    const float* W = (blockIdx.z == 0) ? W0 : (blockIdx.z == 1) ? W1 : W2;
    _Float16* O = Wt + (long)blockIdx.z * 1048576;
    const int tid = threadIdx.x;
    const int kb = blockIdx.y * 64, nb = blockIdx.x * 64;
#pragma unroll
    for (int i = 0; i < 4; i++) {
        int r = (tid >> 4) + i * 16;
        int c = (tid & 15) * 4;
        floatx4 w = *(const floatx4*)&W[(long)(kb + r) * 1024 + nb + c];
#pragma unroll
        for (int j = 0; j < 4; j++) t[(c + j) * 72 + r] = (_Float16)w[j];
    }
    __syncthreads();
    const int c = tid >> 2, rch = (tid & 3) * 16;
    half8 v0 = *(const half8*)&t[c * 72 + rch];
    half8 v1 = *(const half8*)&t[c * 72 + rch + 8];
    _Float16* o = &O[(long)(nb + c) * 1024 + kb + rch];
    *(half8*)o = v0;
    *(half8*)(o + 8) = v1;
}

// ---------------------------------------------------------------------------
// fp32 -> fp16 cast, 8 elems/thread, grid-stride
// ---------------------------------------------------------------------------
__global__ __launch_bounds__(256) void f32_to_f16_kernel(
    const float* __restrict__ in, _Float16* __restrict__ out, int n)
{
    for (long i = ((long)blockIdx.x * 256 + threadIdx.x) * 8; i < n;
         i += (long)gridDim.x * 256 * 8) {
        floatx4 a = *(const floatx4*)&in[i];
        floatx4 b = *(const floatx4*)&in[i + 4];
        half8 h;
#pragma unroll
        for (int e = 0; e < 4; e++) { h[e] = (_Float16)a[e]; h[e + 4] = (_Float16)b[e]; }
        *(half8*)&out[i] = h;
    }
}

// ---------------------------------------------------------------------------
// 256x256 GEMM, one-barrier-per-phase schedule, PEELED TAIL (round-8 exact —
// best verified: 86.7 us, MfmaUtil 33.8%, 0 bank conflicts). Round-9's
// balanced-read register prefetch REGRESSED (cross-phase lgkm pollution) and
// is reverted.
//   C[m][n] = sum_k A[m][k] * Bt[n][k]   (fp16 row-major)
// 512 thr = 8 waves (2Mx4N), per-wave 128x64, BK=64, LDS 128K XOR-swizzled.
//
// Phase = {reads | stage | vmcnt(8)+barrier | MFMA}. Stage slots:
//   p0:(b1,B1,t1) p1:(b1,A1,t1) p2:(b0,A0,t2) p3:(b0,B0,t2)
//   p4:(b0,B1,t2) p5:(b0,A1,t2) p6:(b1,A0,t3) p7:(b1,B0,t3)
// Main loop i < NI-1 with stages UNCONDITIONAL (vmcnt(8) invariant holds at
// every barrier; every read's staging >=4 slots older than its covering
// wait; WAR gaps >=2 barriers). Peeled last iteration stages only b1.B1/A1
// and drains 8,8,8,4,2,0. Verified NI=1 and NI>=2.
// MODE 0: fp16 out (+bias per z)*scale.  MODE 2: fp32 out.
// MODE 1 (NEW): fp16 out TRANSPOSED per batch -> Vt[b][d][t]; K-loop
// identical; epilogue stages C^T through dead smem in 2 passes of
// [128][264] (pad breaks write conflicts), __syncthreads-fenced, then
// block-wide coalesced half8 row stores (batch = m0>>11, t0 = m0&2047;
// 2048%256==0 so a tile never crosses a batch boundary).
// ---------------------------------------------------------------------------
#define STAGE_A(d, h, kt) do { \
    __builtin_amdgcn_global_load_lds((AS1 void*)(Ap + (long)((h) * 64) * lda + (long)(kt) * 64), \
        (AS3 void*)(Ash + (d) * 16384 + (h) * 8192 + sdst), 16, 0, 0); \
    __builtin_amdgcn_global_load_lds((AS1 void*)(Ap + (long)((h) * 64 + 128) * lda + (long)(kt) * 64), \
        (AS3 void*)(Ash + (d) * 16384 + (h) * 8192 + 4096 + sdst), 16, 0, 0); \
} while (0)

#define STAGE_B(d, h, kt) do { \
    __builtin_amdgcn_global_load_lds((AS1 void*)(Bp0 + (long)((h) * 32) * ldb + (long)(kt) * 64), \
        (AS3 void*)(Bsh + (d) * 16384 + (h) * 8192 + sdst), 16, 0, 0); \
    __builtin_amdgcn_global_load_lds((AS1 void*)(Bp1 + (long)((h) * 32) * ldb + (long)(kt) * 64), \
        (AS3 void*)(Bsh + (d) * 16384 + (h) * 8192 + 4096 + sdst), 16, 0, 0); \
} while (0)

#define LDA_FRAGS(d, mh) do { \
    _Pragma("unroll") for (int mi_ = 0; mi_ < 4; mi_++) { \
        const _Float16* p_ = &Ash[(d) * 16384 + (mh) * 8192 + (arow + mi_ * 16) * 64]; \
        aF[mi_][0] = *(const half8*)&p_[kq0]; \
        aF[mi_][1] = *(const half8*)&p_[kq1]; \
    } \
} while (0)

#define LDB_FRAGS(d, nh) do { \
    _Pragma("unroll") for (int ni_ = 0; ni_ < 2; ni_++) { \
        const _Float16* p_ = &Bsh[(d) * 16384 + (nh) * 8192 + (brow + ni_ * 16) * 64]; \
        bF[nh][ni_][0] = *(const half8*)&p_[kq0]; \
        bF[nh][ni_][1] = *(const half8*)&p_[kq1]; \
    } \
} while (0)

#define MFMA16(mh, nh) do { \
    __builtin_amdgcn_s_setprio(1); \
    _Pragma("unroll") for (int mi_ = 0; mi_ < 4; mi_++) \
    _Pragma("unroll") for (int ni_ = 0; ni_ < 2; ni_++) { \
        acc[(mh) * 4 + mi_][(nh) * 2 + ni_] = __builtin_amdgcn_mfma_f32_16x16x32_f16( \
            aF[mi_][0], bF[nh][ni_][0], acc[(mh) * 4 + mi_][(nh) * 2 + ni_], 0, 0, 0); \
        acc[(mh) * 4 + mi_][(nh) * 2 + ni_] = __builtin_amdgcn_mfma_f32_16x16x32_f16( \
            aF[mi_][1], bF[nh][ni_][1], acc[(mh) * 4 + mi_][(nh) * 2 + ni_], 0, 0, 0); \
    } \
    __builtin_amdgcn_s_setprio(0); \
} while (0)

// counted wait + barrier + compiler-only memory fences (one barrier/phase)
#define VMBAR(n) do { \
    asm volatile("s_waitcnt vmcnt(" #n ")" ::: "memory"); \
    __builtin_amdgcn_s_barrier(); \
    asm volatile("" ::: "memory"); \
} while (0)

template <int MODE>
__global__ __launch_bounds__(512, 2) void gemm256_kernel(
    const _Float16* __restrict__ A, const _Float16* __restrict__ Bt,
    void* __restrict__ Cv, const float* __restrict__ bias,
    const float* __restrict__ bias2,
    int nx, int ny, int K, int lda, int ldb, int ldc,
    long aBatch, long bBatch, long cBatch, float scale)
{
    __shared__ _Float16 smem[65536];   // 128 KiB
    _Float16* Ash = smem;
    _Float16* Bsh = smem + 32768;

    const int tid = threadIdx.x;
    const int wave = tid >> 6, lane = tid & 63;
    const int quad = lane >> 4, lr = lane & 15;
    const int wm = wave >> 2, wn = wave & 3;

    // XCD-aware swizzle (grid % 8 == 0 for all our launches)
    const int P = gridDim.x >> 3;
    const int g = (blockIdx.x & 7) * P + (blockIdx.x >> 3);
    const int pplane = nx * ny;
    const int z = g / pplane;
    const int rr = g - z * pplane;
    const int by = rr / nx;
    const int bx = rr - by * nx;
    const int m0 = by * 256, n0 = bx * 256;

    const _Float16* Ab = A + (long)z * aBatch;
    const _Float16* Bb = Bt + (long)z * bBatch;

    // ---- staging geometry: thread -> (local row sr, swizzled 16B chunk) ----
    const int sr0 = tid >> 3;                   // 0..63 (load 0); load 1 adds 64
    const int sc0 = (tid & 7) ^ (sr0 & 7);      // pre-swizzled global chunk
    const _Float16* Ap = Ab + (long)(m0 + sr0) * lda + sc0 * 8;
    const int bc0 = (sr0 & 31) + ((sr0 >> 5) << 6);          // B col, load 0, h=0
    const int bc1 = (sr0 & 31) + (((sr0 >> 5) + 2) << 6);    // B col, load 1, h=0
    const _Float16* Bp0 = Bb + (long)(n0 + bc0) * ldb + sc0 * 8;
    const _Float16* Bp1 = Bb + (long)(n0 + bc1) * ldb + sc0 * 8;
    const int sdst = tid * 8;                   // LDS elem offset (linear dest)

    // ---- fragment-read geometry (k-chunk XOR'd back) ----
    const int kq0 = (quad * 8) ^ ((lr & 7) << 3);
    const int kq1 = (32 + quad * 8) ^ ((lr & 7) << 3);
    const int arow = wm * 64 + lr;              // + mi*16 = A local row
    const int brow = wn * 32 + lr;              // + ni*16 = B local row

    half8 aF[4][2];        // [mi][ks], current A-half
    half8 bF[2][2][2];     // [nh][ni][ks], both B halves live per tile
    floatx4 acc[8][4] = {};
    const int NT = K >> 6;       // even (16 or 32)
    const int NI = NT >> 1;

    // ---- prologue: t0 {A0,B0,B1,A1} + t1 {A0,B0} = 6 half-stages ----
    STAGE_A(0, 0, 0); STAGE_B(0, 0, 0); STAGE_B(0, 1, 0); STAGE_A(0, 1, 0);
    STAGE_A(1, 0, 1); STAGE_B(1, 0, 1);
    asm volatile("s_waitcnt vmcnt(4)" ::: "memory");   // t0's 4 halves landed
    __builtin_amdgcn_s_barrier();
    asm volatile("" ::: "memory");

    // ---- main loop: NI-1 full iterations, stages unconditional ----
    for (int i = 0; i < NI - 1; ++i) {
        const int t1 = 2 * i + 1, t2 = 2 * i + 2, t3 = 2 * i + 3;  // all < NT
        // p0: reads A(b0,h0)+B(b0,h0); stage odd.B1
        LDA_FRAGS(0, 0); LDB_FRAGS(0, 0);
        STAGE_B(1, 1, t1);
        VMBAR(8);
        MFMA16(0, 0);
        // p1: reads B(b0,h1); stage odd.A1
        LDB_FRAGS(0, 1);
        STAGE_A(1, 1, t1);
        VMBAR(8);
        MFMA16(0, 1);
        // p2: reads A(b0,h1); stage even'.A0
        LDA_FRAGS(0, 1);
        STAGE_A(0, 0, t2);
        VMBAR(8);
        MFMA16(1, 1);
        // p3: (no reads, bF0 held); stage even'.B0
        STAGE_B(0, 0, t2);
        VMBAR(8);
        MFMA16(1, 0);
        // p4: reads A(b1,h0)+B(b1,h0); stage even'.B1
        LDA_FRAGS(1, 0); LDB_FRAGS(1, 0);
        STAGE_B(0, 1, t2);
        VMBAR(8);
        MFMA16(0, 0);
        // p5: reads B(b1,h1); stage even'.A1
        LDB_FRAGS(1, 1);
        STAGE_A(0, 1, t2);
        VMBAR(8);
        MFMA16(0, 1);
        // p6: reads A(b1,h1); stage odd'.A0
        LDA_FRAGS(1, 1);
        STAGE_A(1, 0, t3);
        VMBAR(8);
        MFMA16(1, 1);
        // p7: (no reads); stage odd'.B0
        STAGE_B(1, 0, t3);
        VMBAR(8);
        MFMA16(1, 0);
    }

    // ---- peeled last iteration: tiles NT-2 (b0), NT-1 (b1); drain 8,8,8,4,2,0
    {
        const int tl = NT - 1;
        // p0: reads A0,B0(b0) [staged prev p2,p3; covered by prev p7 VMBAR(8)]
        LDA_FRAGS(0, 0); LDB_FRAGS(0, 0);
        STAGE_B(1, 1, tl);
        VMBAR(8);
        MFMA16(0, 0);
        // p1: reads B1(b0) [prev p4; covered]
        LDB_FRAGS(0, 1);
        STAGE_A(1, 1, tl);
        VMBAR(8);
        MFMA16(0, 1);
        // p2: reads A1(b0) [prev p5; covered]
        LDA_FRAGS(0, 1);
        VMBAR(8);
        MFMA16(1, 1);
        // p3: no reads; drain so A0,B0(b1) [prev p6,p7] are landed for p4
        VMBAR(4);
        MFMA16(1, 0);
        // p4: reads A0,B0(b1); drain so B1(b1) [peel p0] lands for p5
        LDA_FRAGS(1, 0); LDB_FRAGS(1, 0);
        VMBAR(2);
        MFMA16(0, 0);
        // p5: reads B1(b1); drain so A1(b1) [peel p1] lands for p6
        LDB_FRAGS(1, 1);
        VMBAR(0);
        MFMA16(0, 1);
        // p6/p7: reads A1(b1) (all staging landed); no more barriers needed
        LDA_FRAGS(1, 1);
        MFMA16(1, 1);
        MFMA16(1, 0);
    }

    // ---- epilogue ----  C/D frag: m = quad*4 + r, n = lane&15
    if constexpr (MODE == 0) {
        _Float16* C = (_Float16*)Cv + (long)z * cBatch;
        const float* bz = (z == 0 || !bias2) ? bias : bias2;
#pragma unroll
        for (int ni = 0; ni < 4; ni++) {
            const int n = n0 + wn * 64 + ni * 16 + lr;
            const float bv_ = bz ? bz[n] : 0.0f;
#pragma unroll
            for (int mi = 0; mi < 8; mi++) {
                const int mb = m0 + wm * 128 + mi * 16 + quad * 4;
#pragma unroll
                for (int r = 0; r < 4; r++)
                    C[(long)(mb + r) * ldc + n] = (_Float16)((acc[mi][ni][r] + bv_) * scale);
            }
        }
    } else if constexpr (MODE == 1) {
        // transposed epilogue: Vt[b][d][t], d = n0+nl, t = m0&2047 + ml.
        // Two passes through dead smem: pass Ph covers nl in [Ph*128, Ph*128+128).
        _Float16* ct = smem;   // [128][264] fp16 = 67.6 KB
        _Float16* C = (_Float16*)Cv + (long)(m0 >> 11) * cBatch;
        const int t0 = m0 & 2047;
#pragma unroll
        for (int Ph = 0; Ph < 2; Ph++) {
            __syncthreads();   // prev pass reads / K-loop reads all done
            if ((wn >> 1) == Ph) {
#pragma unroll
                for (int ni = 0; ni < 4; ni++) {
                    const int nl = wn * 64 + ni * 16 + lr;
                    const int nr = nl & 127;
                    const float bv_ = bias ? bias[n0 + nl] : 0.0f;
#pragma unroll
                    for (int mi = 0; mi < 8; mi++) {
                        const int ml = wm * 128 + mi * 16 + quad * 4;
                        half4 h4;
#pragma unroll
                        for (int r = 0; r < 4; r++)
                            h4[r] = (_Float16)((acc[mi][ni][r] + bv_) * scale);
                        *(half4*)&ct[nr * 264 + ml] = h4;
                    }
                }
            }
            __syncthreads();   // writes visible to all
            // coalesced store: 128 d-rows x 256 t-cols; 4-lane clusters
            // cover 64B contiguous segments.
            const int row = tid >> 2;
            const int cb = (tid & 3) * 8;
#pragma unroll
            for (int j = 0; j < 8; j++) {
                const int col = cb + j * 32;
                half8 v = *(const half8*)&ct[row * 264 + col];
                *(half8*)&C[(long)(n0 + Ph * 128 + row) * ldc + t0 + col] = v;
            }
        }
    } else {
        float* C = (float*)Cv + (long)z * cBatch;
#pragma unroll
        for (int ni = 0; ni < 4; ni++) {
            const int n = n0 + wn * 64 + ni * 16 + lr;
#pragma unroll
            for (int mi = 0; mi < 8; mi++) {
                const int mb = m0 + wm * 128 + mi * 16 + quad * 4;
#pragma unroll
                for (int r = 0; r < 4; r++)
                    C[(long)(mb + r) * ldc + n] = acc[mi][ni][r] * scale;
            }
        }
    }
}

#undef STAGE_A
#undef STAGE_B
#undef LDA_FRAGS
#undef LDB_FRAGS
#undef MFMA16
#undef VMBAR

// ---------------------------------------------------------------------------
// row softmax, in place, fp16. One wave per row of 2048. block=256 -> 4 rows.
// ---------------------------------------------------------------------------
__global__ __launch_bounds__(256) void softmax_kernel(_Float16* __restrict__ buf)
{
    const int lane = threadIdx.x & 63;
    const long row = (long)blockIdx.x * 4 + (threadIdx.x >> 6);
    _Float16* p = buf + row * 2048;

    float f[32];
#pragma unroll
    for (int j = 0; j < 4; j++) {
        half8 v = *(const half8*)&p[lane * 8 + j * 512];
#pragma unroll
        for (int e = 0; e < 8; e++) f[j * 8 + e] = (float)v[e];
    }
    float m = -1e30f;
#pragma unroll
    for (int i = 0; i < 32; i++) m = fmaxf(m, f[i]);
#pragma unroll
    for (int off = 32; off; off >>= 1) m = fmaxf(m, __shfl_xor(m, off, 64));
    float s = 0.0f;
#pragma unroll
    for (int i = 0; i < 32; i++) { f[i] = __expf(f[i] - m); s += f[i]; }
#pragma unroll
    for (int off = 32; off; off >>= 1) s += __shfl_xor(s, off, 64);
    const float inv = 1.0f / s;
#pragma unroll
    for (int j = 0; j < 4; j++) {
        half8 v;
#pragma unroll
        for (int e = 0; e < 8; e++) v[e] = (_Float16)(f[j * 8 + e] * inv);
        *(half8*)&p[lane * 8 + j * 512] = v;
    }
}

// ---------------------------------------------------------------------------
// B=8, S=2048, D=1024.  Workspace layout (bytes):
//   Q   fp16 [16384][1024]            @ 0          (33,554,432)
//   Kb  fp16 [16384][1024]            @ 33,554,432 (33,554,432)   (contig w/ Q)
//   Vt  fp16 [8][1024][2048]          @ 67,108,864 (33,554,432)
//   Sc  fp16 [8][2048][2048]          @ 100,663,296 (67,108,864)  (xb aliased)
//   Wt  fp16 [3][1024][1024]          @ 167,772,160 (6,291,456)
// total 174,063,616
// ---------------------------------------------------------------------------
extern "C" void kernel_launch(void* const* d_in, const int* in_sizes, int n_in,
                              void* d_out, int out_size, void* d_ws, size_t ws_size,
                              hipStream_t stream)
{
    const float* x  = (const float*)d_in[0];
    const float* Wq = (const float*)d_in[1];
    const float* bq = (const float*)d_in[2];
    const float* Wk = (const float*)d_in[3];
    const float* bk = (const float*)d_in[4];
    const float* Wv = (const float*)d_in[5];
    const float* bv = (const float*)d_in[6];

    if (ws_size < 174063616u) return;  // cannot run

    char* ws = (char*)d_ws;
    _Float16* Q  = (_Float16*)(ws + 0);
    _Float16* Vt = (_Float16*)(ws + 67108864);
    _Float16* Sc = (_Float16*)(ws + 100663296);
    _Float16* Wt = (_Float16*)(ws + 167772160);
    _Float16* xb = Sc;  // aliased: xb dead before Sc is written
    _Float16* Kb = Q + 16777216;
    float* out = (float*)d_out;

    wtrans_kernel<<<dim3(16, 16, 3), 256, 0, stream>>>(Wq, Wk, Wv, Wt);
    f32_to_f16_kernel<<<2048, 256, 0, stream>>>(x, xb, 16777216);

    // Q and K projections fused via z: M=16384, N=1024, K=1024 -> 512 blocks
    gemm256_kernel<0><<<512, 512, 0, stream>>>(
        xb, Wt, Q, bq, bk, 4, 64, 1024, 1024, 1024, 1024,
        0, 1048576, 16777216, 1.0f);
    // V projection -> Vt [b][d][t]: gemm256 MODE 1 (transposed epilogue),
    // M=16384, N=1024, K=1024 -> 256 blocks (z=0; batch from m0>>11)
    gemm256_kernel<1><<<256, 512, 0, stream>>>(
        xb, Wt + 2097152, Vt, bv, nullptr, 4, 64, 1024, 1024, 1024, 2048,
        0, 0, 2097152, 1.0f);

    // scores = Q K^T / 32 : per-batch M=N=2048, K=1024 -> 512 blocks
    gemm256_kernel<0><<<512, 512, 0, stream>>>(
        Q, Kb, Sc, nullptr, nullptr, 8, 8, 1024, 1024, 1024, 2048,
        2097152, 2097152, 4194304, 0.03125f);

    softmax_kernel<<<4096, 256, 0, stream>>>(Sc);

    // out = P V : per-batch M=2048, N=1024, K=2048 -> 256 blocks
    gemm256_kernel<2><<<256, 512, 0, stream>>>(
        Sc, Vt, out, nullptr, nullptr, 4, 8, 2048, 2048, 2048, 1024,
        4194304, 2097152, 2097152, 1.0f);
}